// Round 1
// baseline (458.943 us; speedup 1.0000x reference)
//
#include <hip/hip_runtime.h>
#include <hip/hip_bf16.h>

// B=8, N=4096, D=1024, 3 iterations.
// Algebra: fg = (feat @ W_f) @ Wg_mean^T is never materialized.
//   Q[k][d] = sum_j W_f[k,j] * M[d,j]  (M = mean_g W_g), precomputed once.
//   v[b,k]  = q[b,:] . Q[k,:]          (delta[b,n] = feat[b,n,:] . v[b,:])
//   out[b,d]= s[b,:] . Qt[d,:]         (s[b,k] = sum_n c[b,n] feat[b,n,k])
// r6 restructure: 25 launches -> 13. Per iteration only 3 kernels:
//   kmerge {softmax + redundant-per-block q-LN + v-GEMV + zero s}
//   kfeat  {delta + s over the 64 MiB feat stream}
//   kpost  {delta-stats + out-GEMV}
// q-LN is recomputed redundantly in every consumer block (deterministic fp ->
// bitwise identical); q state is double-buffered g_q <-> g_q2 across iters.
// Harness poisons a 512 MiB workspace (~78 us/call, fillBufferAligned in
// rocprof) — unavoidable kernel-side; everything else is ours.

using u16 = unsigned short;
using u32 = unsigned int;
using u8  = unsigned char;
using u64 = unsigned long long;

#define SELU_L 1.0507009873554805f
#define SELU_A 1.6732632423543772f

__device__ float g_M[1048576];   // Wg mean (fp32), [d][j]
__device__ float g_Q[1048576];   // Q[k][d]
__device__ float g_Qt[1048576];  // Qt[d][k] = Q[k][d]
__device__ float g_q[8192];      // q state A (q0, later q2)
__device__ float g_q2[8192];     // q state B (q1)
__device__ float g_s[8192];      // s = c @ feat (atomics; zeroed in kmerge)
__device__ float g_bst[32768];   // b logits state
__device__ float g_c[32768];     // softmax
__device__ float g_delta[32768];
__device__ float g_outv[8192];
__device__ float g_v[8192];
__device__ int   g_dt[12];       // 0..8: 0=bf16,1=f32 per float input; [9]=mask mode

__device__ __forceinline__ float blo(u32 u){ return __uint_as_float(u << 16); }
__device__ __forceinline__ float bhi(u32 u){ return __uint_as_float(u & 0xffff0000u); }
__device__ __forceinline__ float b2f(u16 u){ return __uint_as_float(((u32)u) << 16); }

__device__ __forceinline__ void unpack8(uint4 x, float* f){
  f[0]=blo(x.x); f[1]=bhi(x.x); f[2]=blo(x.y); f[3]=bhi(x.y);
  f[4]=blo(x.z); f[5]=bhi(x.z); f[6]=blo(x.w); f[7]=bhi(x.w);
}

__device__ __forceinline__ float ldf(const void* p, size_t i, int dt){
  return dt ? ((const float*)p)[i] : b2f(((const u16*)p)[i]);
}
__device__ __forceinline__ void load8(const void* base, size_t idx, int dt, float* f){
  if (dt == 0) {
    uint4 x = *(const uint4*)((const u16*)base + idx);
    unpack8(x, f);
  } else {
    const float* p = (const float*)base + idx;
    float4 a = *(const float4*)p, b = *(const float4*)(p + 4);
    f[0]=a.x; f[1]=a.y; f[2]=a.z; f[3]=a.w; f[4]=b.x; f[5]=b.y; f[6]=b.z; f[7]=b.w;
  }
}

__device__ __forceinline__ float wredsum(float x){
#pragma unroll
  for (int o = 32; o; o >>= 1) x += __shfl_xor(x, o, 64);
  return x;
}

// ---- dtype sniffer (wave-parallel) + zero g_q -------------------------------
__global__ void kdet(const void* p0, const void* p1, const void* p2, const void* p3,
                     const void* p4, const void* p5, const void* p6, const void* p7,
                     const void* p8, const void* p9)
{
  const void* ps[10] = {p0,p1,p2,p3,p4,p5,p6,p7,p8,p9};
  int tid = threadIdx.x;
  int w = tid >> 6, lane = tid & 63;
  if (w < 9) {
    const u16* wp = (const u16*)ps[w];
    u16 x0 = wp[lane], x1 = wp[64 + lane];
    int e0 = (x0 >> 7) & 0xFF, e1 = (x1 >> 7) & 0xFF;
    u64 nz0 = __ballot(x0 != 0), nz1 = __ballot(x1 != 0);
    u64 pa0 = __ballot(x0 != 0 && e0 >= 0x70 && e0 <= 0x8F);
    u64 pa1 = __ballot(x1 != 0 && e1 >= 0x70 && e1 <= 0x8F);
    if (lane == 0) {
      const u64 evenm = 0x5555555555555555ULL;   // i parity == lane parity
      int nz = __popcll(nz0) + __popcll(nz1);
      int pass = __popcll(pa0) + __popcll(pa1);
      int evenNZ = __popcll(nz0 & evenm) + __popcll(nz1 & evenm);
      int oddNZ  = nz - evenNZ;
      int dt;
      if (nz == 0)                    dt = 0;
      else if (evenNZ == 0 && oddNZ)  dt = 1;    // f32 signature
      else                            dt = (pass * 10 >= nz * 9) ? 0 : 1;
      g_dt[w] = dt;
    }
  } else if (w == 9) {
    const u8* mp = (const u8*)ps[9];
    u64 v = ((const u64*)mp)[lane];              // bytes lane*8 .. lane*8+7
    bool f16c=false, isF=false, nz01=false, nzNon4=false, nzM8_4=false, anynz=false;
#pragma unroll
    for (int j = 0; j < 8; ++j) {
      u8 cb = (u8)(v >> (8 * j));
      if (!cb) continue;
      int i = lane * 8 + j;
      anynz = true;
      if (cb == 0x3C && (i & 1)) f16c = true;
      if (cb == 0x3F || cb == 0x80) isF = true;
      int m = i & 3;
      if (m == 0 || m == 1) nz01 = true;
      if (m != 0) nzNon4 = true;
      if ((i & 7) == 4) nzM8_4 = true;
    }
    bool A  = __ballot(f16c)   != 0;
    bool Bf = __ballot(isF)    != 0;
    bool C  = __ballot(nz01)   != 0;
    bool Dn = __ballot(nzNon4) != 0;
    bool E  = __ballot(nzM8_4) != 0;
    bool F  = __ballot(anynz)  != 0;
    if (lane == 0) {
      int mode;
      if (A)       mode = 4;                     // f16
      else if (Bf) mode = C ? 2 : 3;             // bf16 : f32
      else if (Dn) mode = 0;                     // u8
      else if (E)  mode = 1;                     // i32
      else if (F)  mode = 5;                     // i64
      else         mode = 1;
      g_dt[9] = mode;
    }
  }
  for (int i = tid; i < 8192; i += 640) g_q[i] = 0.f;
}

// ---- prep: M (blk<1024) | q0 split-64 (blk<1088) | mask (blk<1120) ----------
__global__ void kprep(const void* __restrict__ Wg, const void* __restrict__ Wh,
                      const void* __restrict__ query, const u8* __restrict__ maskp)
{
  int blk = blockIdx.x, tid = threadIdx.x;
  if (blk < 1024) {
    int dtg = g_dt[4];
    int e = blk * 1024 + tid * 4;
    float a0=0.f,a1=0.f,a2=0.f,a3=0.f;
#pragma unroll
    for (int g = 0; g < 4; ++g) {
      size_t o = (size_t)g * 1048576 + e;
      a0 += ldf(Wg, o+0, dtg); a1 += ldf(Wg, o+1, dtg);
      a2 += ldf(Wg, o+2, dtg); a3 += ldf(Wg, o+3, dtg);
    }
    *(float4*)(g_M + e) = make_float4(a0*0.25f, a1*0.25f, a2*0.25f, a3*0.25f);
  } else if (blk < 1088) {
    // q0[b,k] += sum_{d in chunk} query[b,d] * Wh[d,k]; 4 k-tiles x 16 d-chunks
    int dtq = g_dt[0], dth = g_dt[2];
    __shared__ float ql[512];                    // [b][64]
    int blk2 = blk - 1024;
    int kt = blk2 & 3, dc = blk2 >> 2;
    for (int idx = tid; idx < 512; idx += 256) {
      int b = idx >> 6, d = idx & 63;
      ql[idx] = ldf(query, b * 1024 + dc * 64 + d, dtq);
    }
    __syncthreads();
    int k = kt * 256 + tid;
    float acc[8] = {0,0,0,0,0,0,0,0};
    for (int dd = 0; dd < 64; ++dd) {
      int d = dc * 64 + dd;
      float w = ldf(Wh, (size_t)d * 1024 + k, dth);
#pragma unroll
      for (int b = 0; b < 8; ++b) acc[b] += ql[(b << 6) + dd] * w;
    }
#pragma unroll
    for (int b = 0; b < 8; ++b) atomicAdd(&g_q[b * 1024 + k], acc[b]);
  } else {
    int mode = g_dt[9];
    int e0 = (blk - 1088) * 1024 + tid * 4;
#pragma unroll
    for (int j = 0; j < 4; ++j) {
      int e = e0 + j;
      bool on;
      if (mode == 0)      on = maskp[e] != 0;
      else if (mode == 1) on = ((const int*)maskp)[e] != 0;
      else if (mode == 2) on = ((const u16*)maskp)[e] != 0;
      else if (mode == 3) on = ((const u32*)maskp)[e] != 0;
      else if (mode == 4) on = ((const u16*)maskp)[e] != 0;
      else                on = ((const u64*)maskp)[e] != 0ULL;
      g_bst[e] = on ? -1e18f : 0.f;
    }
  }
}

// ---- Q = W_f @ M^T, both layouts, fp32 LDS-tiled 64x64 (one-time) -----------
// Row-major LDS tiles, pad 65 words: a-reads broadcast across tx, b-reads
// land 2-way (free). Scalar b32 LDS ops (pad 65 breaks b128 alignment).
__global__ void __launch_bounds__(256) kq_mat(const void* __restrict__ Wf)
{
  __shared__ float As[64 * 65];
  __shared__ float Bs[64 * 65];
  int tid = threadIdx.x;
  int k0 = (blockIdx.x & 15) * 64, d0 = (blockIdx.x >> 4) * 64;
  int dtf = g_dt[3];
  int tx = tid & 15, ty = tid >> 4;
  float acc[4][4];
#pragma unroll
  for (int i = 0; i < 4; ++i)
#pragma unroll
    for (int l = 0; l < 4; ++l) acc[i][l] = 0.f;

  for (int jc = 0; jc < 1024; jc += 64) {
    if (jc) __syncthreads();                     // prev-iter reads done
#pragma unroll
    for (int t2 = 0; t2 < 2; ++t2) {
      int idx = tid + t2 * 256;
      int row = idx >> 3, seg = idx & 7;
      float f[8];
      load8(Wf, (size_t)(k0 + row) * 1024 + jc + seg * 8, dtf, f);
#pragma unroll
      for (int u = 0; u < 8; ++u) As[row * 65 + seg * 8 + u] = f[u];
      const float* mrow = g_M + (size_t)(d0 + row) * 1024 + jc + seg * 8;
      float4 m0 = *(const float4*)mrow, m1 = *(const float4*)(mrow + 4);
      Bs[row * 65 + seg * 8 + 0] = m0.x; Bs[row * 65 + seg * 8 + 1] = m0.y;
      Bs[row * 65 + seg * 8 + 2] = m0.z; Bs[row * 65 + seg * 8 + 3] = m0.w;
      Bs[row * 65 + seg * 8 + 4] = m1.x; Bs[row * 65 + seg * 8 + 5] = m1.y;
      Bs[row * 65 + seg * 8 + 6] = m1.z; Bs[row * 65 + seg * 8 + 7] = m1.w;
    }
    __syncthreads();
#pragma unroll 8
    for (int j = 0; j < 64; ++j) {
      float a0 = As[(ty * 4 + 0) * 65 + j];
      float a1 = As[(ty * 4 + 1) * 65 + j];
      float a2 = As[(ty * 4 + 2) * 65 + j];
      float a3 = As[(ty * 4 + 3) * 65 + j];
      float b0 = Bs[(tx * 4 + 0) * 65 + j];
      float b1 = Bs[(tx * 4 + 1) * 65 + j];
      float b2 = Bs[(tx * 4 + 2) * 65 + j];
      float b3 = Bs[(tx * 4 + 3) * 65 + j];
      acc[0][0] += a0*b0; acc[0][1] += a0*b1; acc[0][2] += a0*b2; acc[0][3] += a0*b3;
      acc[1][0] += a1*b0; acc[1][1] += a1*b1; acc[1][2] += a1*b2; acc[1][3] += a1*b3;
      acc[2][0] += a2*b0; acc[2][1] += a2*b1; acc[2][2] += a2*b2; acc[2][3] += a2*b3;
      acc[3][0] += a3*b0; acc[3][1] += a3*b1; acc[3][2] += a3*b2; acc[3][3] += a3*b3;
    }
  }
  // Q write (row-major, coalesced float4)
#pragma unroll
  for (int i = 0; i < 4; ++i) {
    *(float4*)(g_Q + (size_t)(k0 + ty * 4 + i) * 1024 + d0 + tx * 4) =
        make_float4(acc[i][0], acc[i][1], acc[i][2], acc[i][3]);
  }
  // Qt via LDS transpose (reuse As), then coalesced float4 out
  __syncthreads();
#pragma unroll
  for (int i = 0; i < 4; ++i)
#pragma unroll
    for (int l = 0; l < 4; ++l) As[(tx * 4 + l) * 65 + ty * 4 + i] = acc[i][l];
  __syncthreads();
  {
    int row = tid >> 2, q4 = tid & 3;            // row = d-local
    float v16[16];
#pragma unroll
    for (int e = 0; e < 16; ++e) v16[e] = As[row * 65 + q4 * 16 + e];
#pragma unroll
    for (int c2 = 0; c2 < 4; ++c2)
      *(float4*)(g_Qt + (size_t)(d0 + row) * 1024 + k0 + q4 * 16 + c2 * 4) =
          make_float4(v16[c2*4], v16[c2*4+1], v16[c2*4+2], v16[c2*4+3]);
  }
}

// ---- redundant q-update into LDS: ql = LN(qsrc + selu(outv*scale)) ----------
__device__ __forceinline__ void build_ql(float* ql, const float* qsrc, float scale,
                                         const void* lnw, const void* lnb, int tid)
{
  int w = tid >> 6, lane = tid & 63;
  int dtw = g_dt[5], dtb = g_dt[6];
#pragma unroll
  for (int rr = 0; rr < 2; ++rr) {
    int b = w + rr * 4;
    const float* qb = qsrc + b * 1024;
    const float* ob = g_outv + b * 1024;
    float x[16]; float sum = 0.f, sq = 0.f;
#pragma unroll
    for (int cc = 0; cc < 4; ++cc) {
      float4 qv = *(const float4*)(qb + cc * 256 + lane * 4);
      float4 ov = *(const float4*)(ob + cc * 256 + lane * 4);
      float q4[4] = {qv.x, qv.y, qv.z, qv.w};
      float o4[4] = {ov.x, ov.y, ov.z, ov.w};
#pragma unroll
      for (int e = 0; e < 4; ++e) {
        float o = o4[e] * scale;
        float se = (o > 0.f) ? SELU_L * o : SELU_L * SELU_A * expm1f(o);
        float val = q4[e] + se;
        x[cc * 4 + e] = val; sum += val; sq += val * val;
      }
    }
    sum = wredsum(sum); sq = wredsum(sq);
    float mean = sum * (1.f / 1024.f);
    float var = fmaxf(sq * (1.f / 1024.f) - mean * mean, 0.f);   // ddof=0
    float rstd = rsqrtf(var + 1e-5f);
#pragma unroll
    for (int cc = 0; cc < 4; ++cc)
#pragma unroll
      for (int e = 0; e < 4; ++e) {
        int d = cc * 256 + lane * 4 + e;
        ql[b * 1024 + d] = (x[cc * 4 + e] - mean) * rstd * ldf(lnw, d, dtw)
                           + ldf(lnb, d, dtb);
      }
  }
  __syncthreads();
}

// ---- merged iteration head: softmax+zero-s (blk<8) | q-LN + v-GEMV (rest) ---
// phase 0: ql = g_q as-is (iter 0).  phase 1: ql = LN(g_q, outv), blk8 -> g_q2.
// phase 2 (last iter, grid=9): blk8 only does LN(g_q2, outv) -> g_q; no GEMV.
__global__ void __launch_bounds__(256) kmerge(const void* __restrict__ lnw,
                                              const void* __restrict__ lnb,
                                              int phase, float scale)
{
  int blk = blockIdx.x, tid = threadIdx.x;
  if (blk < 8) {
    __shared__ float sm[1024];
    int b = blk;
    const float* row = g_bst + b * 4096;
    float mx = -3.4e38f;
    for (int i = tid; i < 4096; i += 256) mx = fmaxf(mx, row[i]);
    sm[tid] = mx; __syncthreads();
    for (int s2 = 128; s2; s2 >>= 1) { if (tid < s2) sm[tid] = fmaxf(sm[tid], sm[tid + s2]); __syncthreads(); }
    mx = sm[0]; __syncthreads();
    float sum = 0.f;
    for (int i = tid; i < 4096; i += 256) {
      float e = __expf(row[i] - mx);
      g_c[b * 4096 + i] = e; sum += e;
    }
    sm[tid] = sum; __syncthreads();
    for (int s2 = 128; s2; s2 >>= 1) { if (tid < s2) sm[tid] += sm[tid + s2]; __syncthreads(); }
    float inv = 1.f / sm[0];
    for (int i = tid; i < 4096; i += 256) g_c[b * 4096 + i] *= inv;
    for (int i = tid; i < 1024; i += 256) g_s[b * 1024 + i] = 0.f;  // zero s for kfeat atomics
    return;
  }
  __shared__ float ql[8192];
  const float* qsrc = (phase == 2) ? g_q2 : g_q;
  if (phase == 0) {
    for (int i = tid; i < 8192; i += 256) ql[i] = qsrc[i];
    __syncthreads();
  } else {
    build_ql(ql, qsrc, scale, lnw, lnb, tid);
  }
  if (phase >= 1 && blk == 8) {
    float* qdst = (phase == 2) ? g_q : g_q2;
    for (int i = tid; i < 8192; i += 256) qdst[i] = ql[i];
  }
  if (phase == 2) return;
  // v-GEMV: wave per k-row of Q
  int w = tid >> 6, lane = tid & 63;
  int k = (blk - 8) * 4 + w;
  const float* Qrow = g_Q + (size_t)k * 1024;
  float f[16];
#pragma unroll
  for (int cc = 0; cc < 4; ++cc) {
    float4 x = *(const float4*)(Qrow + cc * 256 + lane * 4);
    f[cc*4] = x.x; f[cc*4+1] = x.y; f[cc*4+2] = x.z; f[cc*4+3] = x.w;
  }
  float acc[8];
#pragma unroll
  for (int b = 0; b < 8; ++b) {
    const float* qb = ql + b * 1024;
    float d = 0.f;
#pragma unroll
    for (int cc = 0; cc < 4; ++cc) {
      float4 qv = *(const float4*)(qb + cc * 256 + lane * 4);
      d += f[cc*4] * qv.x + f[cc*4+1] * qv.y + f[cc*4+2] * qv.z + f[cc*4+3] * qv.w;
    }
    acc[b] = wredsum(d);
  }
  if (lane == 0) {
#pragma unroll
    for (int b = 0; b < 8; ++b) g_v[b * 1024 + k] = acc[b];
  }
}

// ---- THE big pass over feat: delta[b,n] = feat.v ; s[b,k] += c[n]*feat ------
__global__ void __launch_bounds__(256)
kfeat(const void* __restrict__ feat, int need_delta)
{
  __shared__ float sl[4][1024];
  int tid = threadIdx.x, w = tid >> 6, lane = tid & 63;
  int b = blockIdx.x >> 6, ch = blockIdx.x & 63;
  int dtf = g_dt[1];
  float vr[16];
#pragma unroll
  for (int j = 0; j < 16; ++j) vr[j] = 0.f;
  if (need_delta) {
    const float* vb = g_v + b * 1024;
#pragma unroll
    for (int j = 0; j < 8; ++j) { vr[j] = vb[lane * 8 + j]; vr[8 + j] = vb[512 + lane * 8 + j]; }
  }
  int n0 = ch * 64 + w * 16;
  float cc16[16];
#pragma unroll
  for (int r = 0; r < 16; ++r) cc16[r] = g_c[b * 4096 + n0 + r];  // hoisted, ILP
  float acc[16];
#pragma unroll
  for (int j = 0; j < 16; ++j) acc[j] = 0.f;
  float dp[16];
  for (int r = 0; r < 16; ++r) {
    size_t row = ((size_t)b * 4096 + n0 + r) * 1024;
    float f[16];
    load8(feat, row + lane * 8, dtf, f);
    load8(feat, row + 512 + lane * 8, dtf, f + 8);
    float cn = cc16[r];
#pragma unroll
    for (int j = 0; j < 16; ++j) acc[j] += cn * f[j];
    float dot = 0.f;
    if (need_delta) {
#pragma unroll
      for (int j = 0; j < 16; ++j) dot += f[j] * vr[j];
    }
    dp[r] = dot;
  }
  if (need_delta) {
#pragma unroll
    for (int r = 0; r < 16; ++r) dp[r] = wredsum(dp[r]);   // batched: shfl ILP
    if (lane == 0) {
#pragma unroll
      for (int r = 0; r < 16; ++r) g_delta[b * 4096 + n0 + r] = dp[r];
    }
  }
#pragma unroll
  for (int j = 0; j < 8; ++j) {
    sl[w][lane * 8 + j] = acc[j];
    sl[w][512 + lane * 8 + j] = acc[8 + j];
  }
  __syncthreads();
#pragma unroll
  for (int j = 0; j < 4; ++j) {
    int k = tid * 4 + j;
    float val = sl[0][k] + sl[1][k] + sl[2][k] + sl[3][k];
    atomicAdd(&g_s[b * 1024 + k], val);
  }
}

// ---- merged tail: delta stats (blk<8, if do_stats) | out = s @ Qt (rest) ----
__global__ void __launch_bounds__(256) kpost(int do_stats)
{
  __shared__ float sh[8192];
  int blk = blockIdx.x, tid = threadIdx.x;
  if (blk < 8) {
    if (!do_stats) return;
    int b = blk;
    const float* row = g_delta + b * 4096;
    float xs[16], sum = 0.f, sq = 0.f;
#pragma unroll
    for (int r = 0; r < 16; ++r) { float x = row[tid + 256 * r]; xs[r] = x; sum += x; sq += x * x; }
    sh[tid] = sum; __syncthreads();
    for (int s2 = 128; s2; s2 >>= 1) { if (tid < s2) sh[tid] += sh[tid + s2]; __syncthreads(); }
    sum = sh[0]; __syncthreads();
    sh[tid] = sq; __syncthreads();
    for (int s2 = 128; s2; s2 >>= 1) { if (tid < s2) sh[tid] += sh[tid + s2]; __syncthreads(); }
    sq = sh[0];
    float mean = sum / 4096.f;
    float var = fmaxf((sq - 4096.f * mean * mean) / 4095.f, 0.f);  // ddof=1
    float inv = 1.f / (sqrtf(var) + 1e-9f);
#pragma unroll
    for (int r = 0; r < 16; ++r) {
      int i = tid + 256 * r;
      g_bst[b * 4096 + i] += (xs[r] - mean) * inv;
    }
    return;
  }
  // out-GEMV: wave per d-row of Qt
  for (int i = tid; i < 8192; i += 256) sh[i] = g_s[i];
  __syncthreads();
  int w = tid >> 6, lane = tid & 63;
  int d = (blk - 8) * 4 + w;
  const float* Qtr = g_Qt + (size_t)d * 1024;
  float f[16];
#pragma unroll
  for (int cc = 0; cc < 4; ++cc) {
    float4 x = *(const float4*)(Qtr + cc * 256 + lane * 4);
    f[cc*4] = x.x; f[cc*4+1] = x.y; f[cc*4+2] = x.z; f[cc*4+3] = x.w;
  }
  float acc[8];
#pragma unroll
  for (int b = 0; b < 8; ++b) {
    const float* sb = sh + b * 1024;
    float dd = 0.f;
#pragma unroll
    for (int cc = 0; cc < 4; ++cc) {
      float4 sv = *(const float4*)(sb + cc * 256 + lane * 4);
      dd += f[cc*4] * sv.x + f[cc*4+1] * sv.y + f[cc*4+2] * sv.z + f[cc*4+3] * sv.w;
    }
    acc[b] = wredsum(dd);
  }
  if (lane == 0) {
#pragma unroll
    for (int b = 0; b < 8; ++b) g_outv[b * 1024 + d] = acc[b];   // raw out (scale in LN)
  }
}

// ---- final: q3 = LN(q2 + selu(out2)); out = q3 @ W_out^T + b_out ------------
__global__ void __launch_bounds__(256) kfin(const void* __restrict__ Wout,
                                            const void* __restrict__ bout,
                                            const void* __restrict__ lnw,
                                            const void* __restrict__ lnb,
                                            float* __restrict__ out)
{
  __shared__ float ql[8192];
  int tid = threadIdx.x;
  build_ql(ql, g_q, 1.f, lnw, lnb, tid);         // last iter: no /n
  int w = tid >> 6, lane = tid & 63;
  int o = blockIdx.x * 4 + w;
  int dto = g_dt[7], dtb = g_dt[8];
  size_t row = (size_t)o * 1024;
  float f[16];
  load8(Wout, row + lane * 8, dto, f);
  load8(Wout, row + 512 + lane * 8, dto, f + 8);
  float acc[8];
#pragma unroll
  for (int b = 0; b < 8; ++b) {
    const float* qb = ql + b * 1024;
    float d = 0.f;
#pragma unroll
    for (int j = 0; j < 8; ++j) d += f[j]     * qb[lane * 8 + j];
#pragma unroll
    for (int j = 0; j < 8; ++j) d += f[8 + j] * qb[512 + lane * 8 + j];
    acc[b] = wredsum(d);
  }
  if (lane == 0) {
    float bo = ldf(bout, o, dtb);
#pragma unroll
    for (int b = 0; b < 8; ++b) out[b * 1024 + o] = acc[b] + bo;
  }
}

extern "C" void kernel_launch(void* const* d_in, const int* in_sizes, int n_in,
                              void* d_out, int out_size, void* d_ws, size_t ws_size,
                              hipStream_t stream)
{
  const void* query = d_in[0];
  const void* feat  = d_in[1];
  const void* Wh    = d_in[2];
  const void* Wf    = d_in[3];
  const void* Wg    = d_in[4];
  const void* lnw   = d_in[5];
  const void* lnb   = d_in[6];
  const void* Wout  = d_in[7];
  const void* bout  = d_in[8];
  const u8*   maskp = (const u8*)d_in[9];
  (void)in_sizes; (void)n_in; (void)out_size; (void)d_ws; (void)ws_size;

  kdet<<<1, 640, 0, stream>>>(query, feat, Wh, Wf, Wg, lnw, lnb, Wout, bout, maskp);
  kprep<<<1120, 256, 0, stream>>>(Wg, Wh, query, maskp);
  kq_mat<<<256, 256, 0, stream>>>(Wf);

  for (int i = 0; i < 3; ++i) {
    int nl = (i < 2);                             // non-last iteration
    kmerge<<<(i == 2) ? 9 : 264, 256, 0, stream>>>(lnw, lnb, i, 1.f / 4096.f);
    kfeat<<<512, 256, 0, stream>>>(feat, nl);
    kpost<<<264, 256, 0, stream>>>(nl);
  }
  kfin<<<256, 256, 0, stream>>>(Wout, bout, lnw, lnb, (float*)d_out);
}